// Round 4
// baseline (1319.915 us; speedup 1.0000x reference)
//
#include <hip/hip_runtime.h>
#include <cstdint>
#include <cstddef>

typedef unsigned int u32;
typedef __attribute__((ext_vector_type(8))) short s8v;   // 8 bf16 (4 VGPRs)
typedef __attribute__((ext_vector_type(4))) float f4v;   // MFMA C/D

#define B_   2
#define L_   2048
#define D_   1024
#define NH_  16
#define KVH_ 8
#define DH_  64
#define TOPK_ 1024

#define MFMA16(a, b, c) __builtin_amdgcn_mfma_f32_16x16x32_bf16(a, b, c, 0, 0, 0)

// order-preserving float->uint key (descending float == descending uint)
__device__ __forceinline__ u32 fkey(float s) {
    u32 b = __float_as_uint(s);
    return b ^ ((u32)((int)b >> 31) | 0x80000000u);
}
// fp32 -> bf16 round-to-nearest-even, as raw ushort
__device__ __forceinline__ unsigned short bf16rne(float x) {
    u32 u = __float_as_uint(x);
    u32 r = (u + 0x7FFFu + ((u >> 16) & 1u)) >> 16;
    return (unsigned short)r;
}
__device__ __forceinline__ float bf2f(unsigned short h) {
    return __uint_as_float((u32)h << 16);
}

// ---------------------------------------------------------------------------
// W [K][N] fp32 -> WtH/WtL [N][K] bf16 hi/lo (transpose + split). grid (K/64, N/64)
// ---------------------------------------------------------------------------
__global__ __launch_bounds__(256) void prep_wt(const float* __restrict__ W,
                                               unsigned short* __restrict__ WtH,
                                               unsigned short* __restrict__ WtL,
                                               int K, int N) {
    __shared__ float tile[64 * 65];
    int k0 = blockIdx.x * 64, n0 = blockIdx.y * 64;
    int t = threadIdx.x;
#pragma unroll
    for (int i = 0; i < 16; ++i) {
        int idx = t + i * 256;
        int kk = idx >> 6, nn = idx & 63;
        tile[kk * 65 + nn] = W[(size_t)(k0 + kk) * N + n0 + nn];
    }
    __syncthreads();
#pragma unroll
    for (int i = 0; i < 16; ++i) {
        int idx = t + i * 256;
        int nn = idx >> 6, kk = idx & 63;
        float x = tile[kk * 65 + nn];
        unsigned short hi = bf16rne(x);
        unsigned short lo = bf16rne(x - bf2f(hi));
        WtH[(size_t)(n0 + nn) * K + k0 + kk] = hi;
        WtL[(size_t)(n0 + nn) * K + k0 + kk] = lo;
    }
}

// ---------------------------------------------------------------------------
// MFMA GEMM: C[M][N] fp32 = A[M][K] fp32 @ Wt([N][K] bf16 hi/lo), 3-term hi/lo.
// BM=128, BN=128, BK=32; 256 threads (4 waves, 2x2 of 64x64). grid (M/128, N/128)
// ---------------------------------------------------------------------------
__global__ __launch_bounds__(256) void gemm_mfma(
    const float* __restrict__ A,
    const unsigned short* __restrict__ Wh,
    const unsigned short* __restrict__ Wl,
    float* __restrict__ C, int K, int N) {
    __shared__ __align__(16) unsigned short lAh[128 * 40];
    __shared__ __align__(16) unsigned short lAl[128 * 40];
    __shared__ __align__(16) unsigned short lBh[128 * 40];
    __shared__ __align__(16) unsigned short lBl[128 * 40];
    const int t = threadIdx.x, lane = t & 63, w = t >> 6;
    const int quad = lane >> 4, col = lane & 15;
    const int wm = w >> 1, wn = w & 1;
    const int m0 = blockIdx.x * 128, n0 = blockIdx.y * 128;
    const int sr = t >> 1, sk = (t & 1) * 16;

    f4v acc[4][4];
#pragma unroll
    for (int i = 0; i < 4; ++i)
#pragma unroll
        for (int j = 0; j < 4; ++j) acc[i][j] = (f4v){0.f, 0.f, 0.f, 0.f};

    for (int k0 = 0; k0 < K; k0 += 32) {
        const float* ap = A + (size_t)(m0 + sr) * K + k0 + sk;
        float4 a0 = *(const float4*)(ap);
        float4 a1 = *(const float4*)(ap + 4);
        float4 a2 = *(const float4*)(ap + 8);
        float4 a3 = *(const float4*)(ap + 12);
        s8v bh0 = *(const s8v*)(Wh + (size_t)(n0 + sr) * K + k0 + sk);
        s8v bh1 = *(const s8v*)(Wh + (size_t)(n0 + sr) * K + k0 + sk + 8);
        s8v bl0 = *(const s8v*)(Wl + (size_t)(n0 + sr) * K + k0 + sk);
        s8v bl1 = *(const s8v*)(Wl + (size_t)(n0 + sr) * K + k0 + sk + 8);
        float av[16] = {a0.x, a0.y, a0.z, a0.w, a1.x, a1.y, a1.z, a1.w,
                        a2.x, a2.y, a2.z, a2.w, a3.x, a3.y, a3.z, a3.w};
        union { s8v v; unsigned short u[8]; } ah_[2], al_[2];
#pragma unroll
        for (int i = 0; i < 16; ++i) {
            unsigned short hi = bf16rne(av[i]);
            ah_[i >> 3].u[i & 7] = hi;
            al_[i >> 3].u[i & 7] = bf16rne(av[i] - bf2f(hi));
        }
        __syncthreads();
        *(s8v*)&lAh[sr * 40 + sk]     = ah_[0].v;
        *(s8v*)&lAh[sr * 40 + sk + 8] = ah_[1].v;
        *(s8v*)&lAl[sr * 40 + sk]     = al_[0].v;
        *(s8v*)&lAl[sr * 40 + sk + 8] = al_[1].v;
        *(s8v*)&lBh[sr * 40 + sk]     = bh0;
        *(s8v*)&lBh[sr * 40 + sk + 8] = bh1;
        *(s8v*)&lBl[sr * 40 + sk]     = bl0;
        *(s8v*)&lBl[sr * 40 + sk + 8] = bl1;
        __syncthreads();
        s8v amh[4], aml[4], bnh[4], bnl[4];
#pragma unroll
        for (int mt = 0; mt < 4; ++mt) {
            amh[mt] = *(s8v*)&lAh[(wm * 64 + mt * 16 + col) * 40 + quad * 8];
            aml[mt] = *(s8v*)&lAl[(wm * 64 + mt * 16 + col) * 40 + quad * 8];
        }
#pragma unroll
        for (int nt = 0; nt < 4; ++nt) {
            bnh[nt] = *(s8v*)&lBh[(wn * 64 + nt * 16 + col) * 40 + quad * 8];
            bnl[nt] = *(s8v*)&lBl[(wn * 64 + nt * 16 + col) * 40 + quad * 8];
        }
#pragma unroll
        for (int mt = 0; mt < 4; ++mt)
#pragma unroll
            for (int nt = 0; nt < 4; ++nt) {
                acc[mt][nt] = MFMA16(amh[mt], bnh[nt], acc[mt][nt]);
                acc[mt][nt] = MFMA16(amh[mt], bnl[nt], acc[mt][nt]);
                acc[mt][nt] = MFMA16(aml[mt], bnh[nt], acc[mt][nt]);
            }
    }
#pragma unroll
    for (int mt = 0; mt < 4; ++mt)
#pragma unroll
        for (int nt = 0; nt < 4; ++nt)
#pragma unroll
            for (int r = 0; r < 4; ++r)
                C[(size_t)(m0 + wm * 64 + mt * 16 + quad * 4 + r) * N +
                  n0 + wn * 64 + nt * 16 + col] = acc[mt][nt][r];
}

// ---------------------------------------------------------------------------
// RoPE on Q, in place. Layout [b][l][h][d].
// ---------------------------------------------------------------------------
__global__ __launch_bounds__(256) void rope_q(float* __restrict__ Q,
                                              const int* __restrict__ pos) {
    int tid = blockIdx.x * 256 + threadIdx.x;
    int dl = tid & 31;
    int h  = (tid >> 5) & 15;
    int l  = (tid >> 9) & 2047;
    int b  = tid >> 20;
    size_t base = ((size_t)(b * L_ + l) * NH_ + h) * DH_;
    float x1 = Q[base + dl];
    float x2 = Q[base + dl + 32];
    float p = (float)pos[b * L_ + l];
    float invf = (float)pow(10000.0, -(double)dl / 32.0);
    float a = p * invf;
    float s, c;
    sincosf(a, &s, &c);
    Q[base + dl]      = x1 * c - x2 * s;
    Q[base + dl + 32] = x2 * c + x1 * s;
}

// ---------------------------------------------------------------------------
// RoPE on K + hi/lo bf16 split, layout [b][kvh][l][d]
// ---------------------------------------------------------------------------
__global__ __launch_bounds__(256) void prep_k(const float* __restrict__ Kraw,
                                              unsigned short* __restrict__ KHp,
                                              unsigned short* __restrict__ KLp,
                                              const int* __restrict__ pos) {
    int tid = blockIdx.x * 256 + threadIdx.x;
    int d   = tid & 63;
    int l   = (tid >> 6) & 2047;
    int kvh = (tid >> 17) & 7;
    int b   = tid >> 20;
    size_t src = ((size_t)(b * L_ + l) * KVH_ + kvh) * DH_;
    float x  = Kraw[src + d];
    int dp   = (d < 32) ? d + 32 : d - 32;
    float xp = Kraw[src + dp];
    float p = (float)pos[b * L_ + l];
    int i = d & 31;
    float invf = (float)pow(10000.0, -(double)i / 32.0);
    float a = p * invf;
    float s, c;
    sincosf(a, &s, &c);
    float out = (d < 32) ? (x * c - xp * s) : (x * c + xp * s);
    unsigned short hi = bf16rne(out);
    unsigned short lo = bf16rne(out - bf2f(hi));
    size_t dst = ((size_t)(b * KVH_ + kvh) * L_ + l) * DH_ + d;
    KHp[dst] = hi;
    KLp[dst] = lo;
}

// ---------------------------------------------------------------------------
// V transpose to bf16: Vraw[b][l][kvh][d] -> VT[b][kvh][d][l]
// ---------------------------------------------------------------------------
__global__ __launch_bounds__(256) void prep_v(const float* __restrict__ Vraw,
                                              unsigned short* __restrict__ VTp) {
    __shared__ float tile[64 * 65];
    int bid = blockIdx.x;
    int lb  = bid & 31;
    int kvh = (bid >> 5) & 7;
    int b   = bid >> 8;
    int l0  = lb * 64;
    int t   = threadIdx.x;
#pragma unroll
    for (int i = 0; i < 16; ++i) {
        int idx = t + i * 256;
        int ll = idx >> 6, d = idx & 63;
        tile[ll * 65 + d] = Vraw[((size_t)(b * L_ + l0 + ll) * KVH_ + kvh) * DH_ + d];
    }
    __syncthreads();
#pragma unroll
    for (int i = 0; i < 16; ++i) {
        int idx = t + i * 256;
        int d = idx >> 6, ll = idx & 63;
        VTp[((size_t)(b * KVH_ + kvh) * DH_ + d) * L_ + l0 + ll] = bf16rne(tile[ll * 65 + d]);
    }
}

// ---------------------------------------------------------------------------
// Fused sparse attention, 16 q-rows per block, 1024 threads (16 waves).
// Wave w owns j in [128w, 128w+128): 8 MFMA C-tiles -> S[8] (32 VGPR).
// grid = B*NH*(L/16) = 4096. 16-wave block => 1 block/CU for any VGPR<=512,
// so no launch-bounds register cap (this is what kills the R2/R3 spill).
// Score layout (MFMA C): S[tj][r] = score(q = quad*4+r, j = 128w + 16tj + col)
// ---------------------------------------------------------------------------
__global__ __launch_bounds__(1024) void attn(
    const float* __restrict__ QR,
    const unsigned short* __restrict__ KH,
    const unsigned short* __restrict__ KL,
    const unsigned short* __restrict__ VT,
    float* __restrict__ AO) {

    __shared__ __align__(16) union {
        struct { float qtile[16 * 68]; u32 eqbuf[2048]; } p0;   // phase0 + tie ranking
        u32 hist[16 * 256];                                     // radix (16 KB)
        unsigned short pbuf[16][16 * 36];                       // per-wave P chunks (18 KB)
    } sm;
    __shared__ float outred[16 * 64];                           // fp32 atomic PV reduction
    __shared__ u32 sPref[16], sK[16], sNgt[16], sEqTot[16];
    __shared__ float wredM[16][16], wredZ[16][16], sInvZ[16];
    __shared__ u32 sCM, sRM, eqCnt;

    const int t = threadIdx.x;
    const int lane = t & 63, w = t >> 6;            // w in [0,16)
    const int quad = lane >> 4, col = lane & 15;
    const int bid = blockIdx.x;
    const int l0 = (bid & 127) * 16;
    const int h  = (bid >> 7) & 15;
    const int b  = bid >> 11;
    const int kvh = h >> 1;

    // ---- load Q tile (roped, fp32) into LDS; zero outred
    if (t < 256) {
        int q = t >> 4, d4 = (t & 15) * 4;
        *(float4*)&sm.p0.qtile[q * 68 + d4] =
            *(const float4*)(QR + ((size_t)((b * L_ + l0 + q) * NH_ + h)) * DH_ + d4);
    }
    if (t < 16) { sPref[t] = 0u; sNgt[t] = 0u; sK[t] = TOPK_; sEqTot[t] = 0u; }
    outred[t & 1023] = 0.f;
    __syncthreads();

    // ---- build A-frags (hi/lo): A[m=col][k = ks*32 + quad*8 + i]
    union FR { s8v v; unsigned short u[8]; };
    FR ah[2], al[2];
#pragma unroll
    for (int ks = 0; ks < 2; ++ks)
#pragma unroll
        for (int i = 0; i < 8; ++i) {
            float x = sm.p0.qtile[col * 68 + ks * 32 + quad * 8 + i];
            unsigned short hi = bf16rne(x);
            ah[ks].u[i] = hi;
            al[ks].u[i] = bf16rne(x - bf2f(hi));
        }
    __syncthreads();

    // ---- QK^T via MFMA, 4-term hi/lo (fp32-class accuracy for exact top-k)
    const size_t slabK = (size_t)(b * KVH_ + kvh) * L_ * DH_;
    const unsigned short* khp = KH + slabK;
    const unsigned short* klp = KL + slabK;
    f4v S[8];
#pragma unroll
    for (int tj = 0; tj < 8; ++tj) {
        int j0 = w * 128 + tj * 16;
        const unsigned short* kh8 = khp + (size_t)(j0 + col) * 64 + quad * 8;
        const unsigned short* kl8 = klp + (size_t)(j0 + col) * 64 + quad * 8;
        s8v bh0 = *(const s8v*)(kh8);
        s8v bh1 = *(const s8v*)(kh8 + 32);
        s8v bl0 = *(const s8v*)(kl8);
        s8v bl1 = *(const s8v*)(kl8 + 32);
        f4v c = {0.f, 0.f, 0.f, 0.f};
        c = MFMA16(ah[0].v, bh0, c);
        c = MFMA16(al[0].v, bh0, c);
        c = MFMA16(ah[1].v, bh1, c);
        c = MFMA16(al[1].v, bh1, c);
        c = MFMA16(ah[0].v, bl0, c);
        c = MFMA16(al[0].v, bl0, c);
        c = MFMA16(ah[1].v, bl1, c);
        c = MFMA16(al[1].v, bl1, c);
        S[tj] = c * 0.125f;   // DH^-0.5
    }

    // ---- exact top-1024 per row: 4-pass 8-bit radix select on fkey
    for (int pass = 0; pass < 4; ++pass) {
        int shift = 24 - 8 * pass;
#pragma unroll
        for (int i = 0; i < 4; ++i) sm.hist[t * 4 + i] = 0u;
        __syncthreads();
        u32 pm  = pass ? (0xFFFFFFFFu << (shift + 8)) : 0u;
        u32 pf0 = sPref[quad * 4 + 0], pf1 = sPref[quad * 4 + 1];
        u32 pf2 = sPref[quad * 4 + 2], pf3 = sPref[quad * 4 + 3];
#pragma unroll
        for (int tj = 0; tj < 8; ++tj) {
            u32 u;
            u = fkey(S[tj][0]); if ((u & pm) == pf0) atomicAdd(&sm.hist[(quad * 4 + 0) * 256 + ((u >> shift) & 255)], 1u);
            u = fkey(S[tj][1]); if ((u & pm) == pf1) atomicAdd(&sm.hist[(quad * 4 + 1) * 256 + ((u >> shift) & 255)], 1u);
            u = fkey(S[tj][2]); if ((u & pm) == pf2) atomicAdd(&sm.hist[(quad * 4 + 2) * 256 + ((u >> shift) & 255)], 1u);
            u = fkey(S[tj][3]); if ((u & pm) == pf3) atomicAdd(&sm.hist[(quad * 4 + 3) * 256 + ((u >> shift) & 255)], 1u);
        }
        __syncthreads();
        // wave w resolves row q = w
        {
            u32* hq = &sm.hist[w * 256];
            u32 h0 = hq[4 * lane], h1 = hq[4 * lane + 1];
            u32 h2 = hq[4 * lane + 2], h3 = hq[4 * lane + 3];
            u32 s4 = h0 + h1 + h2 + h3;
            u32 v = s4;
            for (int off = 1; off < 64; off <<= 1) {
                u32 tmp = __shfl_down(v, off);
                if (lane + off < 64) v += tmp;
            }
            u32 g = v - s4;
            u32 kq = sK[w];
            u32 hb_[4] = {h0, h1, h2, h3};
#pragma unroll
            for (int bb = 3; bb >= 0; --bb) {
                u32 hb = hb_[bb];
                if (hb && g < kq && kq <= g + hb) {
                    sPref[w] |= ((u32)(4 * lane + bb)) << shift;
                    sK[w]   = kq - g;
                    sNgt[w] += g;
                }
                g += hb;
            }
        }
        __syncthreads();
    }

    // ---- selection masks (bit tj per reg r), exact tie handling
    u32 uth0 = sPref[quad * 4 + 0], uth1 = sPref[quad * 4 + 1];
    u32 uth2 = sPref[quad * 4 + 2], uth3 = sPref[quad * 4 + 3];
    u32 selb[4] = {0u, 0u, 0u, 0u};
    {
        u32 e0 = 0, e1 = 0, e2 = 0, e3 = 0;
#pragma unroll
        for (int tj = 0; tj < 8; ++tj) {
            u32 u;
            u = fkey(S[tj][0]); if (u > uth0) selb[0] |= 1u << tj; else if (u == uth0) e0++;
            u = fkey(S[tj][1]); if (u > uth1) selb[1] |= 1u << tj; else if (u == uth1) e1++;
            u = fkey(S[tj][2]); if (u > uth2) selb[2] |= 1u << tj; else if (u == uth2) e2++;
            u = fkey(S[tj][3]); if (u > uth3) selb[3] |= 1u << tj; else if (u == uth3) e3++;
        }
        if (e0) atomicAdd(&sEqTot[quad * 4 + 0], e0);
        if (e1) atomicAdd(&sEqTot[quad * 4 + 1], e1);
        if (e2) atomicAdd(&sEqTot[quad * 4 + 2], e2);
        if (e3) atomicAdd(&sEqTot[quad * 4 + 3], e3);
    }
    __syncthreads();
    if (t == 0) {
        u32 cm = 0, rm = 0;
        for (int q = 0; q < 16; ++q) {
            u32 quo = (u32)TOPK_ - sNgt[q];
            if (sEqTot[q] == quo) cm |= 1u << q; else rm |= 1u << q;
        }
        sCM = cm; sRM = rm;
    }
    __syncthreads();
    {
        u32 cm = sCM;
        bool c0 = (cm >> (quad * 4 + 0)) & 1u, c1 = (cm >> (quad * 4 + 1)) & 1u;
        bool c2 = (cm >> (quad * 4 + 2)) & 1u, c3 = (cm >> (quad * 4 + 3)) & 1u;
#pragma unroll
        for (int tj = 0; tj < 8; ++tj) {
            if (c0 && fkey(S[tj][0]) == uth0) selb[0] |= 1u << tj;
            if (c1 && fkey(S[tj][1]) == uth1) selb[1] |= 1u << tj;
            if (c2 && fkey(S[tj][2]) == uth2) selb[2] |= 1u << tj;
            if (c3 && fkey(S[tj][3]) == uth3) selb[3] |= 1u << tj;
        }
    }
    {   // rare rows: rank ties by lowest index
        u32 rm = sRM;
        for (int q = 0; q < 16; ++q) {
            if (!((rm >> q) & 1u)) continue;
            if (t == 0) eqCnt = 0u;
            __syncthreads();
            u32 uq = sPref[q];
            int qq = q >> 2, qr = q & 3;
            if (quad == qq) {
#pragma unroll
                for (int r = 0; r < 4; ++r) if (r == qr) {
#pragma unroll
                    for (int tj = 0; tj < 8; ++tj)
                        if (fkey(S[tj][r]) == uq) {
                            u32 idx = atomicAdd(&eqCnt, 1u);
                            if (idx < 2048u) sm.p0.eqbuf[idx] = (u32)(w * 128 + tj * 16 + col);
                        }
                }
            }
            __syncthreads();
            u32 m = eqCnt; if (m > 2048u) m = 2048u;
            u32 quo = (u32)TOPK_ - sNgt[q];
            if (quad == qq) {
#pragma unroll
                for (int r = 0; r < 4; ++r) if (r == qr) {
#pragma unroll
                    for (int tj = 0; tj < 8; ++tj)
                        if (fkey(S[tj][r]) == uq) {
                            u32 j = (u32)(w * 128 + tj * 16 + col);
                            u32 rk = 0;
                            for (u32 i = 0; i < m; ++i)
                                if (sm.p0.eqbuf[i] < j) rk++;
                            if (rk < quo) selb[r] |= 1u << tj;
                        }
                }
            }
            __syncthreads();
        }
    }

    // ---- softmax (row max over all scores; top element always selected)
    float m0 = -3.4e38f, m1 = -3.4e38f, m2 = -3.4e38f, m3 = -3.4e38f;
#pragma unroll
    for (int tj = 0; tj < 8; ++tj) {
        m0 = fmaxf(m0, S[tj][0]); m1 = fmaxf(m1, S[tj][1]);
        m2 = fmaxf(m2, S[tj][2]); m3 = fmaxf(m3, S[tj][3]);
    }
    for (int off = 1; off < 16; off <<= 1) {
        m0 = fmaxf(m0, __shfl_xor(m0, off)); m1 = fmaxf(m1, __shfl_xor(m1, off));
        m2 = fmaxf(m2, __shfl_xor(m2, off)); m3 = fmaxf(m3, __shfl_xor(m3, off));
    }
    if (col == 0) {
        wredM[quad * 4 + 0][w] = m0; wredM[quad * 4 + 1][w] = m1;
        wredM[quad * 4 + 2][w] = m2; wredM[quad * 4 + 3][w] = m3;
    }
    __syncthreads();
    {
        float a0 = wredM[quad * 4 + 0][0], a1 = wredM[quad * 4 + 1][0];
        float a2 = wredM[quad * 4 + 2][0], a3 = wredM[quad * 4 + 3][0];
#pragma unroll
        for (int ww = 1; ww < 16; ++ww) {
            a0 = fmaxf(a0, wredM[quad * 4 + 0][ww]); a1 = fmaxf(a1, wredM[quad * 4 + 1][ww]);
            a2 = fmaxf(a2, wredM[quad * 4 + 2][ww]); a3 = fmaxf(a3, wredM[quad * 4 + 3][ww]);
        }
        m0 = a0; m1 = a1; m2 = a2; m3 = a3;
    }
    float z0 = 0.f, z1 = 0.f, z2 = 0.f, z3 = 0.f;
#pragma unroll
    for (int tj = 0; tj < 8; ++tj) {
        float e;
        e = ((selb[0] >> tj) & 1u) ? __expf(S[tj][0] - m0) : 0.f; S[tj][0] = e; z0 += e;
        e = ((selb[1] >> tj) & 1u) ? __expf(S[tj][1] - m1) : 0.f; S[tj][1] = e; z1 += e;
        e = ((selb[2] >> tj) & 1u) ? __expf(S[tj][2] - m2) : 0.f; S[tj][2] = e; z2 += e;
        e = ((selb[3] >> tj) & 1u) ? __expf(S[tj][3] - m3) : 0.f; S[tj][3] = e; z3 += e;
    }
    for (int off = 1; off < 16; off <<= 1) {
        z0 += __shfl_xor(z0, off); z1 += __shfl_xor(z1, off);
        z2 += __shfl_xor(z2, off); z3 += __shfl_xor(z3, off);
    }
    if (col == 0) {
        wredZ[quad * 4 + 0][w] = z0; wredZ[quad * 4 + 1][w] = z1;
        wredZ[quad * 4 + 2][w] = z2; wredZ[quad * 4 + 3][w] = z3;
    }
    __syncthreads();
    if (w == 0 && col == 0) {
#pragma unroll
        for (int r = 0; r < 4; ++r) {
            int q = quad * 4 + r;
            float Z = 0.f;
#pragma unroll
            for (int ww = 0; ww < 16; ++ww) Z += wredZ[q][ww];
            sInvZ[q] = 1.f / Z;
        }
    }

    // ---- PV via MFMA; wave w covers its 128-col j-range in 4 chunks of 32.
    const unsigned short* vt = VT + (size_t)(b * KVH_ + kvh) * DH_ * L_;
    f4v acc0 = {0.f, 0.f, 0.f, 0.f}, acc1 = acc0, acc2 = acc0, acc3 = acc0;
#pragma unroll
    for (int cc = 0; cc < 4; ++cc) {
        // write P chunk (C-layout -> row-major [q][jl]) — wave-private region
#pragma unroll
        for (int tjl = 0; tjl < 2; ++tjl) {
            int tj = cc * 2 + tjl;
            sm.pbuf[w][(quad * 4 + 0) * 36 + tjl * 16 + col] = bf16rne(S[tj][0]);
            sm.pbuf[w][(quad * 4 + 1) * 36 + tjl * 16 + col] = bf16rne(S[tj][1]);
            sm.pbuf[w][(quad * 4 + 2) * 36 + tjl * 16 + col] = bf16rne(S[tj][2]);
            sm.pbuf[w][(quad * 4 + 3) * 36 + tjl * 16 + col] = bf16rne(S[tj][3]);
        }
        // same-wave DS ordering guarantees write->read consistency
        s8v ap = *(const s8v*)&sm.pbuf[w][col * 36 + quad * 8];
        int jb = w * 128 + cc * 32 + quad * 8;
        s8v v0 = *(const s8v*)(vt + (size_t)( 0 + col) * L_ + jb);
        s8v v1 = *(const s8v*)(vt + (size_t)(16 + col) * L_ + jb);
        s8v v2 = *(const s8v*)(vt + (size_t)(32 + col) * L_ + jb);
        s8v v3 = *(const s8v*)(vt + (size_t)(48 + col) * L_ + jb);
        acc0 = MFMA16(ap, v0, acc0);
        acc1 = MFMA16(ap, v1, acc1);
        acc2 = MFMA16(ap, v2, acc2);
        acc3 = MFMA16(ap, v3, acc3);
    }

    // ---- cross-wave PV reduction via LDS fp32 atomics, then scale + store
#pragma unroll
    for (int r = 0; r < 4; ++r) {
        atomicAdd(&outred[(quad * 4 + r) * 64 +  0 + col], acc0[r]);
        atomicAdd(&outred[(quad * 4 + r) * 64 + 16 + col], acc1[r]);
        atomicAdd(&outred[(quad * 4 + r) * 64 + 32 + col], acc2[r]);
        atomicAdd(&outred[(quad * 4 + r) * 64 + 48 + col], acc3[r]);
    }
    __syncthreads();
    if (t < 256) {
        int q = t >> 4, d4 = (t & 15) * 4;
        float4 o = *(float4*)&outred[q * 64 + d4];
        float iz = sInvZ[q];
        o.x *= iz; o.y *= iz; o.z *= iz; o.w *= iz;
        *(float4*)(AO + ((size_t)((b * L_ + l0 + q) * NH_ + h)) * DH_ + d4) = o;
    }
}

// ---------------------------------------------------------------------------
extern "C" void kernel_launch(void* const* d_in, const int* in_sizes, int n_in,
                              void* d_out, int out_size, void* d_ws, size_t ws_size,
                              hipStream_t stream) {
    const float* hs = (const float*)d_in[0];
    const float* wq = (const float*)d_in[1];
    const float* wk = (const float*)d_in[2];
    const float* wv = (const float*)d_in[3];
    const float* wo = (const float*)d_in[4];
    const int*  pos = (const int*)d_in[5];

    float* ws = (float*)d_ws;
    const size_t M1 = 1u << 20;
    float* Qraw = ws;                          // [0, 4M) floats
    float* Kraw = ws + 4 * M1;                 // [4M, 6M) — dead after prep_k
    float* Vraw = ws + 6 * M1;                 // [6M, 8M) — dead after prep_v
    float* AO   = ws + 4 * M1;                 // [4M, 8M) overlays Kraw+Vraw
    unsigned short* WqH = (unsigned short*)(ws +  8 * M1);            // 1M shorts
    unsigned short* WqL = (unsigned short*)(ws +  8 * M1 + M1 / 2);
    unsigned short* WkH = (unsigned short*)(ws +  9 * M1);            // 0.5M shorts
    unsigned short* WkL = (unsigned short*)(ws +  9 * M1 + M1 / 4);
    unsigned short* WvH = (unsigned short*)(ws +  9 * M1 + M1 / 2);
    unsigned short* WvL = (unsigned short*)(ws +  9 * M1 + 3 * (M1 / 4));
    unsigned short* WoH = (unsigned short*)(ws + 10 * M1);            // 1M shorts
    unsigned short* WoL = (unsigned short*)(ws + 10 * M1 + M1 / 2);
    unsigned short* KH  = (unsigned short*)(ws + 11 * M1);            // 2M shorts
    unsigned short* KL  = (unsigned short*)(ws + 12 * M1);
    unsigned short* VT  = (unsigned short*)(ws + 13 * M1);
    float* out = (float*)d_out;

    dim3 blk(256);
    prep_wt<<<dim3(16, 16), blk, 0, stream>>>(wq, WqH, WqL, 1024, 1024);
    prep_wt<<<dim3(16,  8), blk, 0, stream>>>(wk, WkH, WkL, 1024, 512);
    prep_wt<<<dim3(16,  8), blk, 0, stream>>>(wv, WvH, WvL, 1024, 512);
    prep_wt<<<dim3(16, 16), blk, 0, stream>>>(wo, WoH, WoL, 1024, 1024);
    gemm_mfma<<<dim3(32, 8), blk, 0, stream>>>(hs, WqH, WqL, Qraw, 1024, 1024);
    gemm_mfma<<<dim3(32, 4), blk, 0, stream>>>(hs, WkH, WkL, Kraw, 1024, 512);
    gemm_mfma<<<dim3(32, 4), blk, 0, stream>>>(hs, WvH, WvL, Vraw, 1024, 512);
    rope_q<<<dim3(8192), blk, 0, stream>>>(Qraw, pos);
    prep_k<<<dim3(8192), blk, 0, stream>>>(Kraw, KH, KL, pos);
    prep_v<<<dim3(512),  blk, 0, stream>>>(Vraw, VT);
    attn<<<dim3(4096), dim3(1024), 0, stream>>>(Qraw, KH, KL, VT, AO);
    gemm_mfma<<<dim3(32, 8), blk, 0, stream>>>(AO, WoH, WoL, out, 1024, 1024);
}